// Round 3
// baseline (286.014 us; speedup 1.0000x reference)
//
#include <hip/hip_runtime.h>

#define HW_DIM 4096
#define NHW 32            // hw positions per block
#define NT 512            // threads: 32 hw x 16 d-pairs
#define VSTR 289          // v LDS row stride (odd pad -> conflict-free reads)
#define PSTR 113          // probs LDS hw-stride (odd), rows at i*13

__global__ __launch_bounds__(NT, 6)
void attn9_kernel(const float* __restrict__ logits,
                  const float* __restrict__ v,
                  float* __restrict__ out)
{
    __shared__ float v_s[NHW * VSTR];   // 36,992 B
    __shared__ float p_s[NHW * PSTR];   // 14,464 B

    const int t = threadIdx.x;
    const int bid = blockIdx.x;
    const int chunk = bid & (HW_DIM / NHW - 1);   // 0..127
    const int bh = bid >> 7;                      // b*8 + h, 0..31

    const int hw0 = bh * HW_DIM + chunk * NHW;    // flattened (b,h,hw) base

    // ---- stage V tile into LDS: coalesced float4 global reads, padded b32 LDS writes ----
    {
        const float4* vg = reinterpret_cast<const float4*>(v + (size_t)hw0 * 288);
        #pragma unroll
        for (int k = 0; k < 5; ++k) {
            int idx4 = t + k * NT;
            if (idx4 < (NHW * 288) / 4) {
                float4 val = vg[idx4];
                int fi = idx4 * 4;
                int hwl = fi / 288;
                int r = fi - hwl * 288;
                float* dst = &v_s[hwl * VSTR + r];
                dst[0] = val.x; dst[1] = val.y; dst[2] = val.z; dst[3] = val.w;
            }
        }
    }

    // ---- softmax: thread t < 288 owns row (hwl, i); reads logits direct from global ----
    if (t < NHW * 9) {
        const int hwl = t / 9;
        const int i = t - hwl * 9;
        const float* lg = logits + (size_t)(hw0 + hwl) * 81 + i * 9;
        float x[9];
        #pragma unroll
        for (int j = 0; j < 9; ++j)
            x[j] = __builtin_nontemporal_load(lg + j) * 0.17677669529663687f;
        float m = x[0];
        #pragma unroll
        for (int j = 1; j < 9; ++j) m = fmaxf(m, x[j]);
        float e[9];
        float s = 0.f;
        #pragma unroll
        for (int j = 0; j < 9; ++j) { e[j] = expf(x[j] - m); s += e[j]; }
        const float inv = 1.0f / (s + 1e-12f);
        float* pr = &p_s[hwl * PSTR + i * 13];
        #pragma unroll
        for (int j = 0; j < 9; ++j) pr[j] = e[j] * inv;
    }

    __syncthreads();

    // ---- compute out[i][d0..d0+1] for own (hw, d-pair); direct coalesced nt stores ----
    const int hw = t & (NHW - 1);
    const int dg = t >> 5;        // 0..15
    const int d0 = dg * 2;

    float va[9], vb[9];
    const float* vrow = &v_s[hw * VSTR + d0];
    #pragma unroll
    for (int j = 0; j < 9; ++j) { va[j] = vrow[j * 32]; vb[j] = vrow[j * 32 + 1]; }

    float* ob = out + (size_t)bh * 288 * HW_DIM + chunk * NHW + hw;
    const float* prow = &p_s[hw * PSTR];
    #pragma unroll
    for (int i = 0; i < 9; ++i) {
        float a0 = 0.f, a1 = 0.f;
        #pragma unroll
        for (int j = 0; j < 9; ++j) {
            float p = prow[i * 13 + j];
            a0 = fmaf(p, va[j], a0);
            a1 = fmaf(p, vb[j], a1);
        }
        __builtin_nontemporal_store(a0, &ob[(size_t)(d0 * 9 + i) * HW_DIM]);
        __builtin_nontemporal_store(a1, &ob[(size_t)((d0 + 1) * 9 + i) * HW_DIM]);
    }
}

extern "C" void kernel_launch(void* const* d_in, const int* in_sizes, int n_in,
                              void* d_out, int out_size, void* d_ws, size_t ws_size,
                              hipStream_t stream) {
    const float* logits = (const float*)d_in[0];
    const float* v      = (const float*)d_in[1];
    float* out          = (float*)d_out;
    const int grid = 4 * 8 * (HW_DIM / NHW);   // 4096 blocks
    attn9_kernel<<<grid, NT, 0, stream>>>(logits, v, out);
}